// Round 17
// baseline (25.381 us; speedup 1.0000x reference)
//
#include <hip/hip_runtime.h>
#include <hip/hip_fp16.h>

// Problem constants (match reference)
constexpr int B  = 4;
constexpr int C  = 3;
constexpr int F  = 5;
constexpr int HO = 256;
constexpr int WO = 256;
constexpr int HI = HO + F - 1; // 260
constexpr int WI = WO + F - 1; // 260
constexpr int P  = HO * WO;    // 65536 pixels per (b, map)
constexpr int FF = F * F;      // 25
constexpr int PI = HI * WI;    // 67600 input pixels per (b, c)

// R17 = R16 (2 px/thread, 24.75us) + 2-deep stream prefetch + margin 6->5.
// Block = 256 threads = 4 waves: wave = (row in {0,1}) x (tap-half in {0,1}).
// Patch = 128 px wide x 2 rows; thread handles (x, x+1); streams are float2.
// Streams pipelined 2-deep (cur/n1/n2 named structs -> SROA to regs; ~30
// persistent floats, safe at 256-thr blocks where VGPR cap is 128 — the
// R13/R14 spills were the 512-thread 64-VGPR pin).
// Tile: rows [y0-6, y0+10] (17) x cols [x0-6, x0+136] (143), fp16 uint2;
// margin 5: P(|N|>5)~6e-7 -> ~8 global-fallback events per run, free.
// TSTRIDE = 149 (mod 16 = 5): R15's bank-decollision carried over.
constexpr int TROWS = 17;
constexpr int TCOLS = 143;
constexpr int TSTRIDE = 149;           // 8B units
constexpr int TN = TROWS * TCOLS;      // 2431 entries to stage
constexpr int AMAX = (TROWS - 2) * TSTRIDE + (TCOLS - 2); // 2376

__device__ __forceinline__ float2 ld2(const float* p) {
    return *reinterpret_cast<const float2*>(p);
}

__device__ __forceinline__ uint2 pack3(float a, float b, float c) {
    __half2 ab = __floats2half2_rn(a, b);
    __half2 cz = __floats2half2_rn(c, 0.0f);
    uint2 r;
    r.x = *reinterpret_cast<const unsigned int*>(&ab);
    r.y = *reinterpret_cast<const unsigned int*>(&cz);
    return r;
}

__device__ __forceinline__ void fmacc(uint2 v, float w,
                                      float& a0, float& a1, float& a2) {
    __half2 ab = *reinterpret_cast<const __half2*>(&v.x);
    __half2 cz = *reinterpret_cast<const __half2*>(&v.y);
    // (float)half * f32 + f32 acc -> v_fma_mix_f32
    a0 += __half2float(__low2half(ab))  * w;
    a1 += __half2float(__high2half(ab)) * w;
    a2 += __half2float(__low2half(cz))  * w;
}

struct Streams {            // named fields only -> SROA scalarizes to regs
    float2 oy, ox, mk, h, v;
};

__device__ __forceinline__ void loadStreams(
    int k, Streams& s,
    const float* __restrict__ offYb, const float* __restrict__ offXb,
    const float* __restrict__ maskb, const float* __restrict__ vb,
    const float* __restrict__ hb)
{
    const int i = k / F;
    const int j = k - i * F;
    s.oy = ld2(offYb + (size_t)k * P);
    s.ox = ld2(offXb + (size_t)k * P);
    s.mk = ld2(maskb + (size_t)k * P);
    s.h  = ld2(hb + (size_t)j * P);
    s.v  = ld2(vb + (size_t)i * P);
}

__global__ __launch_bounds__(256, 4) void dsepconv_kernel(
    const float* __restrict__ inp,   // (B, C, HI, WI)
    const float* __restrict__ vert,  // (B, F, HO, WO)
    const float* __restrict__ horz,  // (B, F, HO, WO)
    const float* __restrict__ offX,  // -> py (vertical), per reference
    const float* __restrict__ offY,  // -> px (horizontal), per reference
    const float* __restrict__ mask,  // (B, F*F, HO, WO)
    float* __restrict__ out)         // (B, C, HO, WO)
{
    __shared__ uint2 tileq[TROWS * TSTRIDE];  // 20,264 B
    __shared__ float red[2][3][128];          // 3,072 B: half-1 partials

    const int tid  = threadIdx.x;
    const int lane = tid & 63;
    const int wave = tid >> 6;                 // 0..3
    const int wrow = wave >> 1;                // 0..1: y-row in patch
    const int half = wave & 1;                 // 0..1: tap half

    // Grid: bx = b*256 + yblk*2 + xblk ; patch origin (y0, x0)
    const int bx   = blockIdx.x;
    const int x0   = (bx & 1) * 128;
    const int y0   = ((bx >> 1) & 127) * 2;
    const int b    = bx >> 8;

    const float* in0 = inp + (size_t)b * C * PI;
    const float* in1 = in0 + PI;
    const float* in2 = in1 + PI;

    const int x   = x0 + 2 * lane;             // even; this thread: x, x+1
    const int y   = y0 + wrow;
    const int pix = y * WO + x;

    const float* offXb = offX + (size_t)b * FF * P + pix;
    const float* offYb = offY + (size_t)b * FF * P + pix;
    const float* maskb = mask + (size_t)b * FF * P + pix;
    const float* vb    = vert + (size_t)b * F * P + pix;
    const float* hb    = horz + (size_t)b * F * P + pix;

    const int k0    = half ? 12 : 0;
    const int k1    = half ? 25 : 12;
    const int klast = k1 - 1;

    // ---- 2-deep stream prefetch (drains under the staging barrier) ----
    Streams cur, n1, n2;
    loadStreams(k0, cur, offYb, offXb, maskb, vb, hb);
    loadStreams(min(k0 + 1, klast), n1, offYb, offXb, maskb, vb, hb);

    // ---- Stage tile: rows [y0-6, y0+10], cols [x0-6, x0+136] ----
    const int ry0 = y0 - 6;
    const int cx0 = x0 - 6;
#pragma unroll 1
    for (int e = tid; e < TN; e += 256) {
        int trow = e / TCOLS;
        int tcol = e - trow * TCOLS;
        int gy = min(max(ry0 + trow, 0), HI - 1);
        int gx = min(max(cx0 + tcol, 0), WI - 1);
        int g = gy * WI + gx;
        tileq[trow * TSTRIDE + tcol] = pack3(in0[g], in1[g], in2[g]);
    }
    __syncthreads();   // vmcnt(0) drain also completes the stream prefetch

    float acc0a = 0.f, acc1a = 0.f, acc2a = 0.f;
    float acc0b = 0.f, acc1b = 0.f, acc2b = 0.f;

#pragma unroll 1
    for (int k = k0; k < k1; ++k) {
        const int i = k / F;
        const int j = k - i * F;

        // ---- issue streams for tap k+2 (2-deep: stays in flight across
        //      this tap's AND the next tap's compute) ----
        loadStreams(min(k + 2, klast), n2, offYb, offXb, maskb, vb, hb);

        // ---- coords, pixel A (x) and B (x+1), from cur (in regs) ----
        // px = clip(offY + x + j - half + 1, 0, WI-1); half = 2
        float pya = fminf(fmaxf(cur.ox.x + (float)(y + i - 1), 0.0f), (float)(HI - 1));
        float pyb = fminf(fmaxf(cur.ox.y + (float)(y + i - 1), 0.0f), (float)(HI - 1));
        float pxa = fminf(fmaxf(cur.oy.x + (float)(x + j - 1), 0.0f), (float)(WI - 1));
        float pxb = fminf(fmaxf(cur.oy.y + (float)(x + j), 0.0f), (float)(WI - 1));

        float lfa = floorf(pxa), tfa = floorf(pya);
        float lfb = floorf(pxb), tfb = floorf(pyb);
        int la = (int)lfa, ta = (int)tfa;
        int lb = (int)lfb, tb = (int)tfb;
        float wxa = 1.0f - (pxa - lfa), wya = 1.0f - (pya - tfa);
        float wxb = 1.0f - (pxb - lfb), wyb = 1.0f - (pyb - tfb);

        int lta = ta - ry0, lla = la - cx0;
        int ltb = tb - ry0, llb = lb - cx0;
        bool oka = ((unsigned)lta <= TROWS - 2) & ((unsigned)lla <= TCOLS - 2);
        bool okb = ((unsigned)ltb <= TROWS - 2) & ((unsigned)llb <= TCOLS - 2);

        int aa = min(max(lta * TSTRIDE + lla, 0), AMAX);
        int ab = min(max(ltb * TSTRIDE + llb, 0), AMAX);

        // ---- 8 gathers issue together; FMAs follow ----
        uint2 ga0 = tileq[aa];
        uint2 ga1 = tileq[aa + 1];
        uint2 ga2 = tileq[aa + TSTRIDE];
        uint2 ga3 = tileq[aa + TSTRIDE + 1];
        uint2 gb0 = tileq[ab];
        uint2 gb1 = tileq[ab + 1];
        uint2 gb2 = tileq[ab + TSTRIDE];
        uint2 gb3 = tileq[ab + TSTRIDE + 1];

        // rare fallback: offset beyond tile margin (~1e-6/sample)
        if (__any(!(oka & okb))) {
            if (!oka) {
                int r  = min(la + 1, WI - 1);
                int bt = min(ta + 1, HI - 1);
                int o0 = ta * WI + la, o1 = ta * WI + r;
                int o2 = bt * WI + la, o3 = bt * WI + r;
                ga0 = pack3(in0[o0], in1[o0], in2[o0]);
                ga1 = pack3(in0[o1], in1[o1], in2[o1]);
                ga2 = pack3(in0[o2], in1[o2], in2[o2]);
                ga3 = pack3(in0[o3], in1[o3], in2[o3]);
            }
            if (!okb) {
                int r  = min(lb + 1, WI - 1);
                int bt = min(tb + 1, HI - 1);
                int o0 = tb * WI + lb, o1 = tb * WI + r;
                int o2 = bt * WI + lb, o3 = bt * WI + r;
                gb0 = pack3(in0[o0], in1[o0], in2[o0]);
                gb1 = pack3(in0[o1], in1[o1], in2[o1]);
                gb2 = pack3(in0[o2], in1[o2], in2[o2]);
                gb3 = pack3(in0[o3], in1[o3], in2[o3]);
            }
        }

        // Bilinear identity: clamped edge => r/bottom weights exactly 0.
        float wA   = cur.v.x * cur.h.x * cur.mk.x;
        float wywA = wya * wA;
        float wbwA = wA - wywA;
        float wtlA = wxa * wywA;
        float wtrA = wywA - wtlA;
        float wblA = wxa * wbwA;
        float wbrA = wbwA - wblA;

        float wB   = cur.v.y * cur.h.y * cur.mk.y;
        float wywB = wyb * wB;
        float wbwB = wB - wywB;
        float wtlB = wxb * wywB;
        float wtrB = wywB - wtlB;
        float wblB = wxb * wbwB;
        float wbrB = wbwB - wblB;

        fmacc(ga0, wtlA, acc0a, acc1a, acc2a);
        fmacc(ga1, wtrA, acc0a, acc1a, acc2a);
        fmacc(ga2, wblA, acc0a, acc1a, acc2a);
        fmacc(ga3, wbrA, acc0a, acc1a, acc2a);
        fmacc(gb0, wtlB, acc0b, acc1b, acc2b);
        fmacc(gb1, wtrB, acc0b, acc1b, acc2b);
        fmacc(gb2, wblB, acc0b, acc1b, acc2b);
        fmacc(gb3, wbrB, acc0b, acc1b, acc2b);

        // ---- rotate stream pipeline ----
        cur = n1;
        n1  = n2;
    }

    // ---- Combine the two tap-halves per row (float2 traffic) ----
    if (half) {
        *reinterpret_cast<float2*>(&red[wrow][0][2 * lane]) = make_float2(acc0a, acc0b);
        *reinterpret_cast<float2*>(&red[wrow][1][2 * lane]) = make_float2(acc1a, acc1b);
        *reinterpret_cast<float2*>(&red[wrow][2][2 * lane]) = make_float2(acc2a, acc2b);
    }
    __syncthreads();

    if (!half) {
        float* ob = out + (size_t)b * C * P + pix;
        float2 r0 = *reinterpret_cast<const float2*>(&red[wrow][0][2 * lane]);
        float2 r1 = *reinterpret_cast<const float2*>(&red[wrow][1][2 * lane]);
        float2 r2 = *reinterpret_cast<const float2*>(&red[wrow][2][2 * lane]);
        *reinterpret_cast<float2*>(&ob[0])     = make_float2(acc0a + r0.x, acc0b + r0.y);
        *reinterpret_cast<float2*>(&ob[P])     = make_float2(acc1a + r1.x, acc1b + r1.y);
        *reinterpret_cast<float2*>(&ob[2 * P]) = make_float2(acc2a + r2.x, acc2b + r2.y);
    }
}

extern "C" void kernel_launch(void* const* d_in, const int* in_sizes, int n_in,
                              void* d_out, int out_size, void* d_ws, size_t ws_size,
                              hipStream_t stream) {
    const float* inp  = (const float*)d_in[0];
    const float* vert = (const float*)d_in[1];
    const float* horz = (const float*)d_in[2];
    const float* offX = (const float*)d_in[3];
    const float* offY = (const float*)d_in[4];
    const float* mask = (const float*)d_in[5];
    float* out = (float*)d_out;

    // grid: B * (HO/2) * (WO/128) = 4 * 128 * 2 = 1024 blocks, 256 thr each
    dim3 block(256);
    dim3 grid(B * (HO / 2) * (WO / 128));
    dsepconv_kernel<<<grid, block, 0, stream>>>(inp, vert, horz, offX, offY, mask, out);
}

// Round 18
// 23.490 us; speedup vs baseline: 1.0805x; 1.0805x over previous
//
#include <hip/hip_runtime.h>
#include <hip/hip_fp16.h>

// Problem constants (match reference)
constexpr int B  = 4;
constexpr int C  = 3;
constexpr int F  = 5;
constexpr int HO = 256;
constexpr int WO = 256;
constexpr int HI = HO + F - 1; // 260
constexpr int WI = WO + F - 1; // 260
constexpr int P  = HO * WO;    // 65536 pixels per (b, map)
constexpr int FF = F * F;      // 25
constexpr int PI = HI * WI;    // 67600 input pixels per (b, c)

// R18 = R16 (2 px/thread, 1-deep stream prefetch, 24.75us) +
//   (a) staging loop unrolled x4: iterations are independent + transient,
//       so unrolling pipelines the 3 global loads/iter (the staging loop was
//       a serial load-use chain, ~6k cy/block exposed); tap-loop unroll 1
//       stays (persistent-state widening spills: R3/R5/R13/R14).
//   (b) margin 6->5 (validated in R17: passed, absmax unchanged): TN -12%.
// Block = 256 threads = 4 waves: wave = (row in {0,1}) x (tap-half in {0,1}).
// Patch = 128 px wide x 2 rows; thread handles (x, x+1); streams are float2.
// Tile: rows [y0-6, y0+10] (17) x cols [x0-6, x0+136] (143), fp16 uint2.
// TSTRIDE = 149 (mod 16 = 5): R15's bank-decollision carried over.
constexpr int TROWS = 17;
constexpr int TCOLS = 143;
constexpr int TSTRIDE = 149;           // 8B units
constexpr int TN = TROWS * TCOLS;      // 2431 entries to stage
constexpr int AMAX = (TROWS - 2) * TSTRIDE + (TCOLS - 2); // 2376

__device__ __forceinline__ float2 ld2(const float* p) {
    return *reinterpret_cast<const float2*>(p);
}

__device__ __forceinline__ uint2 pack3(float a, float b, float c) {
    __half2 ab = __floats2half2_rn(a, b);
    __half2 cz = __floats2half2_rn(c, 0.0f);
    uint2 r;
    r.x = *reinterpret_cast<const unsigned int*>(&ab);
    r.y = *reinterpret_cast<const unsigned int*>(&cz);
    return r;
}

__device__ __forceinline__ void fmacc(uint2 v, float w,
                                      float& a0, float& a1, float& a2) {
    __half2 ab = *reinterpret_cast<const __half2*>(&v.x);
    __half2 cz = *reinterpret_cast<const __half2*>(&v.y);
    // (float)half * f32 + f32 acc -> v_fma_mix_f32
    a0 += __half2float(__low2half(ab))  * w;
    a1 += __half2float(__high2half(ab)) * w;
    a2 += __half2float(__low2half(cz))  * w;
}

__global__ __launch_bounds__(256, 4) void dsepconv_kernel(
    const float* __restrict__ inp,   // (B, C, HI, WI)
    const float* __restrict__ vert,  // (B, F, HO, WO)
    const float* __restrict__ horz,  // (B, F, HO, WO)
    const float* __restrict__ offX,  // -> py (vertical), per reference
    const float* __restrict__ offY,  // -> px (horizontal), per reference
    const float* __restrict__ mask,  // (B, F*F, HO, WO)
    float* __restrict__ out)         // (B, C, HO, WO)
{
    __shared__ uint2 tileq[TROWS * TSTRIDE];  // 20,264 B
    __shared__ float red[2][3][128];          // 3,072 B: half-1 partials

    const int tid  = threadIdx.x;
    const int lane = tid & 63;
    const int wave = tid >> 6;                 // 0..3
    const int wrow = wave >> 1;                // 0..1: y-row in patch
    const int half = wave & 1;                 // 0..1: tap half

    // Grid: bx = b*256 + yblk*2 + xblk ; patch origin (y0, x0)
    const int bx   = blockIdx.x;
    const int x0   = (bx & 1) * 128;
    const int y0   = ((bx >> 1) & 127) * 2;
    const int b    = bx >> 8;

    const float* in0 = inp + (size_t)b * C * PI;
    const float* in1 = in0 + PI;
    const float* in2 = in1 + PI;

    const int x   = x0 + 2 * lane;             // even; this thread: x, x+1
    const int y   = y0 + wrow;
    const int pix = y * WO + x;

    const float* offXb = offX + (size_t)b * FF * P + pix;
    const float* offYb = offY + (size_t)b * FF * P + pix;
    const float* maskb = mask + (size_t)b * FF * P + pix;
    const float* vb    = vert + (size_t)b * F * P + pix;
    const float* hb    = horz + (size_t)b * F * P + pix;

    const int k0 = half ? 12 : 0;
    const int k1 = half ? 25 : 12;

    // ---- Prefetch first tap's streams (drained by the staging barrier) ----
    float2 oy, ox, m, h, v;
    {
        const int i = k0 / F, j = k0 - (k0 / F) * F;
        oy = ld2(offYb + (size_t)k0 * P);
        ox = ld2(offXb + (size_t)k0 * P);
        m  = ld2(maskb + (size_t)k0 * P);
        h  = ld2(hb + (size_t)j * P);
        v  = ld2(vb + (size_t)i * P);
    }

    // ---- Stage tile: rows [y0-6, y0+10], cols [x0-6, x0+136] ----
    // Unroll 4: iterations independent, state transient -> loads pipeline
    // without persistent-VGPR growth (unlike tap-loop widening).
    const int ry0 = y0 - 6;
    const int cx0 = x0 - 6;
#pragma unroll 4
    for (int e = tid; e < TN; e += 256) {
        int trow = e / TCOLS;
        int tcol = e - trow * TCOLS;
        int gy = min(max(ry0 + trow, 0), HI - 1);
        int gx = min(max(cx0 + tcol, 0), WI - 1);
        int g = gy * WI + gx;
        tileq[trow * TSTRIDE + tcol] = pack3(in0[g], in1[g], in2[g]);
    }
    __syncthreads();   // vmcnt(0) drain also completes the stream prefetch

    float acc0a = 0.f, acc1a = 0.f, acc2a = 0.f;
    float acc0b = 0.f, acc1b = 0.f, acc2b = 0.f;

#pragma unroll 1
    for (int k = k0; k < k1; ++k) {
        const int i = k / F;
        const int j = k - i * F;

        // ---- issue NEXT tap's streams (float2, overlap with compute) ----
        const int kn  = (k + 1 < k1) ? k + 1 : k;
        const int in_ = kn / F;
        const int jn  = kn - in_ * F;
        float2 oy_n = ld2(offYb + (size_t)kn * P);
        float2 ox_n = ld2(offXb + (size_t)kn * P);
        float2 m_n  = ld2(maskb + (size_t)kn * P);
        float2 h_n  = ld2(hb + (size_t)jn * P);
        float2 v_n  = ld2(vb + (size_t)in_ * P);

        // ---- coords, pixel A (x) and B (x+1) ----
        // px = clip(offY + x + j - half + 1, 0, WI-1); half = 2
        float pya = fminf(fmaxf(ox.x + (float)(y + i - 1), 0.0f), (float)(HI - 1));
        float pyb = fminf(fmaxf(ox.y + (float)(y + i - 1), 0.0f), (float)(HI - 1));
        float pxa = fminf(fmaxf(oy.x + (float)(x + j - 1), 0.0f), (float)(WI - 1));
        float pxb = fminf(fmaxf(oy.y + (float)(x + j), 0.0f), (float)(WI - 1));

        float lfa = floorf(pxa), tfa = floorf(pya);
        float lfb = floorf(pxb), tfb = floorf(pyb);
        int la = (int)lfa, ta = (int)tfa;
        int lb = (int)lfb, tb = (int)tfb;
        float wxa = 1.0f - (pxa - lfa), wya = 1.0f - (pya - tfa);
        float wxb = 1.0f - (pxb - lfb), wyb = 1.0f - (pyb - tfb);

        int lta = ta - ry0, lla = la - cx0;
        int ltb = tb - ry0, llb = lb - cx0;
        bool oka = ((unsigned)lta <= TROWS - 2) & ((unsigned)lla <= TCOLS - 2);
        bool okb = ((unsigned)ltb <= TROWS - 2) & ((unsigned)llb <= TCOLS - 2);

        int aa = min(max(lta * TSTRIDE + lla, 0), AMAX);
        int ab = min(max(ltb * TSTRIDE + llb, 0), AMAX);

        // ---- 8 gathers issue together; FMAs follow ----
        uint2 ga0 = tileq[aa];
        uint2 ga1 = tileq[aa + 1];
        uint2 ga2 = tileq[aa + TSTRIDE];
        uint2 ga3 = tileq[aa + TSTRIDE + 1];
        uint2 gb0 = tileq[ab];
        uint2 gb1 = tileq[ab + 1];
        uint2 gb2 = tileq[ab + TSTRIDE];
        uint2 gb3 = tileq[ab + TSTRIDE + 1];

        // rare fallback: offset beyond tile margin (~1e-6/sample; R17-validated)
        if (__any(!(oka & okb))) {
            if (!oka) {
                int r  = min(la + 1, WI - 1);
                int bt = min(ta + 1, HI - 1);
                int o0 = ta * WI + la, o1 = ta * WI + r;
                int o2 = bt * WI + la, o3 = bt * WI + r;
                ga0 = pack3(in0[o0], in1[o0], in2[o0]);
                ga1 = pack3(in0[o1], in1[o1], in2[o1]);
                ga2 = pack3(in0[o2], in1[o2], in2[o2]);
                ga3 = pack3(in0[o3], in1[o3], in2[o3]);
            }
            if (!okb) {
                int r  = min(lb + 1, WI - 1);
                int bt = min(tb + 1, HI - 1);
                int o0 = tb * WI + lb, o1 = tb * WI + r;
                int o2 = bt * WI + lb, o3 = bt * WI + r;
                gb0 = pack3(in0[o0], in1[o0], in2[o0]);
                gb1 = pack3(in0[o1], in1[o1], in2[o1]);
                gb2 = pack3(in0[o2], in1[o2], in2[o2]);
                gb3 = pack3(in0[o3], in1[o3], in2[o3]);
            }
        }

        // Bilinear identity: clamped edge => r/bottom weights exactly 0.
        float wA   = v.x * h.x * m.x;
        float wywA = wya * wA;
        float wbwA = wA - wywA;
        float wtlA = wxa * wywA;
        float wtrA = wywA - wtlA;
        float wblA = wxa * wbwA;
        float wbrA = wbwA - wblA;

        float wB   = v.y * h.y * m.y;
        float wywB = wyb * wB;
        float wbwB = wB - wywB;
        float wtlB = wxb * wywB;
        float wtrB = wywB - wtlB;
        float wblB = wxb * wbwB;
        float wbrB = wbwB - wblB;

        fmacc(ga0, wtlA, acc0a, acc1a, acc2a);
        fmacc(ga1, wtrA, acc0a, acc1a, acc2a);
        fmacc(ga2, wblA, acc0a, acc1a, acc2a);
        fmacc(ga3, wbrA, acc0a, acc1a, acc2a);
        fmacc(gb0, wtlB, acc0b, acc1b, acc2b);
        fmacc(gb1, wtrB, acc0b, acc1b, acc2b);
        fmacc(gb2, wblB, acc0b, acc1b, acc2b);
        fmacc(gb3, wbrB, acc0b, acc1b, acc2b);

        // ---- rotate stream pipeline ----
        oy = oy_n; ox = ox_n; m = m_n; h = h_n; v = v_n;
    }

    // ---- Combine the two tap-halves per row (float2 traffic) ----
    if (half) {
        *reinterpret_cast<float2*>(&red[wrow][0][2 * lane]) = make_float2(acc0a, acc0b);
        *reinterpret_cast<float2*>(&red[wrow][1][2 * lane]) = make_float2(acc1a, acc1b);
        *reinterpret_cast<float2*>(&red[wrow][2][2 * lane]) = make_float2(acc2a, acc2b);
    }
    __syncthreads();

    if (!half) {
        float* ob = out + (size_t)b * C * P + pix;
        float2 r0 = *reinterpret_cast<const float2*>(&red[wrow][0][2 * lane]);
        float2 r1 = *reinterpret_cast<const float2*>(&red[wrow][1][2 * lane]);
        float2 r2 = *reinterpret_cast<const float2*>(&red[wrow][2][2 * lane]);
        *reinterpret_cast<float2*>(&ob[0])     = make_float2(acc0a + r0.x, acc0b + r0.y);
        *reinterpret_cast<float2*>(&ob[P])     = make_float2(acc1a + r1.x, acc1b + r1.y);
        *reinterpret_cast<float2*>(&ob[2 * P]) = make_float2(acc2a + r2.x, acc2b + r2.y);
    }
}

extern "C" void kernel_launch(void* const* d_in, const int* in_sizes, int n_in,
                              void* d_out, int out_size, void* d_ws, size_t ws_size,
                              hipStream_t stream) {
    const float* inp  = (const float*)d_in[0];
    const float* vert = (const float*)d_in[1];
    const float* horz = (const float*)d_in[2];
    const float* offX = (const float*)d_in[3];
    const float* offY = (const float*)d_in[4];
    const float* mask = (const float*)d_in[5];
    float* out = (float*)d_out;

    // grid: B * (HO/2) * (WO/128) = 4 * 128 * 2 = 1024 blocks, 256 thr each
    dim3 block(256);
    dim3 grid(B * (HO / 2) * (WO / 128));
    dsepconv_kernel<<<grid, block, 0, stream>>>(inp, vert, horz, offX, offY, mask, out);
}